// Round 5
// baseline (995.425 us; speedup 1.0000x reference)
//
#include <hip/hip_runtime.h>
#include <math.h>

#define NB 16
#define SL 32
#define H5 5120
#define K3 3072

typedef __attribute__((ext_vector_type(8))) short short8;
typedef __attribute__((ext_vector_type(4))) float floatx4;

__device__ __forceinline__ float sigf(float x) { return 1.0f / (1.0f + expf(-x)); }

__device__ __forceinline__ unsigned short f2bf(float x) {
  union { float f; unsigned int u; } v;
  v.f = x;
  unsigned int r = v.u + 0x7FFFu + ((v.u >> 16) & 1u);
  return (unsigned short)(r >> 16);
}

// meta layout (ints):
//  own 0, lt 512, li 1024, rt 1536, ri 2048, dep 2560, nn 3072(16),
//  dcnt 3088(32), lcnt 3120(32), dlist 3152(32*512), llist 19536(32*512)
// ksplit: separate array, 16 * 32 * 33 ints, [b*1056 + s*33 + l]

// ---------------- zero ----------------
__global__ void k_zero(float* __restrict__ p, int n) {
  int i = blockIdx.x * blockDim.x + threadIdx.x;
  if (i < n) p[i] = 0.0f;
}

// ---------------- batch f32 -> bf16 conversion (6 segments) ----------------
__global__ void k_conv6(const float* s0, unsigned short* d0, int n0,
                        const float* s1, unsigned short* d1, int n1,
                        const float* s2, unsigned short* d2, int n2,
                        const float* s3, unsigned short* d3, int n3,
                        const float* s4, unsigned short* d4, int n4,
                        const float* s5, unsigned short* d5, int n5)
{
  const float* s; unsigned short* d; int n;
  switch (blockIdx.y) {
    case 0: s = s0; d = d0; n = n0; break;
    case 1: s = s1; d = d1; n = n1; break;
    case 2: s = s2; d = d2; n = n2; break;
    case 3: s = s3; d = d3; n = n3; break;
    case 4: s = s4; d = d4; n = n4; break;
    default: s = s5; d = d5; n = n5; break;
  }
  const int nf4 = n >> 2;
  for (int i = blockIdx.x * blockDim.x + threadIdx.x; i < nf4; i += gridDim.x * blockDim.x) {
    const float4 v = *(const float4*)&s[i * 4];
    ushort4 o;
    o.x = f2bf(v.x); o.y = f2bf(v.y); o.z = f2bf(v.z); o.w = f2bf(v.w);
    *(ushort4*)&d[i * 4] = o;
  }
}

// ---- generic f32 GEMM (only used for E1): out[r,g] = sum_k A[r,k]*W[g,k]
__global__ __launch_bounds__(256)
void k_gemm(const float* __restrict__ A, int lda,
            const float* __restrict__ W, int ldw,
            float* __restrict__ out, int N, int K)
{
  __shared__ __align__(16) float sm[2 * 16 * 68];
  float* As = sm;
  float* Ws = sm + 16 * 68;
  const int tid = threadIdx.x;
  const int tx = tid & 15, ty = tid >> 4;
  const int g0 = blockIdx.x * 64, r0 = blockIdx.y * 64;
  float acc[4][4];
#pragma unroll
  for (int i = 0; i < 4; ++i)
#pragma unroll
    for (int j = 0; j < 4; ++j) acc[i][j] = 0.0f;
  const int ks = tid & 15, rr = tid >> 4;
  for (int kt = 0; kt < K; kt += 16) {
#pragma unroll
    for (int rep = 0; rep < 4; ++rep) {
      As[ks * 68 + rep * 16 + rr] = A[(size_t)(r0 + rep * 16 + rr) * lda + kt + ks];
      Ws[ks * 68 + rep * 16 + rr] = W[(size_t)(g0 + rep * 16 + rr) * ldw + kt + ks];
    }
    __syncthreads();
#pragma unroll
    for (int k = 0; k < 16; ++k) {
      const float4 a4 = *(const float4*)&As[k * 68 + ty * 4];
      const float4 w4 = *(const float4*)&Ws[k * 68 + tx * 4];
      const float av[4] = {a4.x, a4.y, a4.z, a4.w};
      const float wv[4] = {w4.x, w4.y, w4.z, w4.w};
#pragma unroll
      for (int i = 0; i < 4; ++i)
#pragma unroll
        for (int j = 0; j < 4; ++j) acc[i][j] += av[i] * wv[j];
    }
    __syncthreads();
  }
#pragma unroll
  for (int i = 0; i < 4; ++i) {
    const int r = r0 + ty * 4 + i;
    float4 o;
    o.x = acc[i][0]; o.y = acc[i][1]; o.z = acc[i][2]; o.w = acc[i][3];
    *(float4*)&out[(size_t)r * N + g0 + tx * 4] = o;
  }
}

// ---------------- input projection MFMA: X = embB @ WihB^T ----------------
__global__ __launch_bounds__(256)
void k_xproj(const unsigned short* __restrict__ embB,
             const unsigned short* __restrict__ WfB, const unsigned short* __restrict__ WbB,
             float* __restrict__ Xf, float* __restrict__ Xb)
{
  const unsigned short* B = blockIdx.z ? WbB : WfB;
  float* out = blockIdx.z ? Xb : Xf;
  __shared__ __align__(16) unsigned short As[128 * 40];
  __shared__ __align__(16) unsigned short Bs[128 * 40];
  const int tid = threadIdx.x;
  const int g0 = blockIdx.x * 128;
  const int r0 = blockIdx.y * 128;
  const int wave = tid >> 6, lane = tid & 63;
  const int wm = wave >> 1, wn = wave & 1;
  const int l15 = lane & 15, quad = lane >> 4;
  floatx4 acc[4][4];
#pragma unroll
  for (int mt = 0; mt < 4; ++mt)
#pragma unroll
    for (int nt = 0; nt < 4; ++nt) acc[mt][nt] = (floatx4){0.f, 0.f, 0.f, 0.f};
  for (int kt = 0; kt < 512; kt += 32) {
    __syncthreads();
#pragma unroll
    for (int p = 0; p < 2; ++p) {
      const int i = tid + p * 256;
      const int row = i >> 2, q = i & 3;
      *(uint4*)&As[row * 40 + q * 8] = *(const uint4*)&embB[(size_t)(r0 + row) * 512 + kt + q * 8];
      *(uint4*)&Bs[row * 40 + q * 8] = *(const uint4*)&B[(size_t)(g0 + row) * 512 + kt + q * 8];
    }
    __syncthreads();
    short8 af[4], bfr[4];
#pragma unroll
    for (int mt = 0; mt < 4; ++mt)
      af[mt] = *(const short8*)&As[(wm * 64 + mt * 16 + l15) * 40 + quad * 8];
#pragma unroll
    for (int nt = 0; nt < 4; ++nt)
      bfr[nt] = *(const short8*)&Bs[(wn * 64 + nt * 16 + l15) * 40 + quad * 8];
#pragma unroll
    for (int mt = 0; mt < 4; ++mt)
#pragma unroll
      for (int nt = 0; nt < 4; ++nt)
        acc[mt][nt] = __builtin_amdgcn_mfma_f32_16x16x32_bf16(af[mt], bfr[nt], acc[mt][nt], 0, 0, 0);
  }
#pragma unroll
  for (int nt = 0; nt < 4; ++nt) {
    const int col = g0 + wn * 64 + nt * 16 + l15;
#pragma unroll
    for (int mt = 0; mt < 4; ++mt)
#pragma unroll
      for (int i = 0; i < 4; ++i) {
        const int row = r0 + wm * 64 + mt * 16 + quad * 4 + i;
        out[(size_t)row * 2048 + col] = acc[mt][nt][i];
      }
  }
}

// ---------------- big compose GEMM: gB[r,g] = bc[g] + U @ WcB^T ----------------
__global__ __launch_bounds__(256)
void k_mfma_gemm(const unsigned short* __restrict__ U, const unsigned short* __restrict__ WcB,
                 const float* __restrict__ bc, float* __restrict__ gB)
{
  __shared__ __align__(16) unsigned short As[128 * 40];
  __shared__ __align__(16) unsigned short Bs[64 * 40];
  const int bid = blockIdx.x;
  const int r0 = (bid / 80) * 128;
  const int g0 = (bid % 80) * 64;
  const int tid = threadIdx.x;
  const int wave = tid >> 6, lane = tid & 63;
  const int wm = wave >> 1, wn = wave & 1;
  const int l15 = lane & 15, quad = lane >> 4;
  floatx4 acc[4][2];
#pragma unroll
  for (int mf = 0; mf < 4; ++mf)
#pragma unroll
    for (int nt = 0; nt < 2; ++nt) acc[mf][nt] = (floatx4){0.f, 0.f, 0.f, 0.f};
  const int a_row = tid >> 2, a_q = tid & 3;
  for (int kt = 0; kt < K3; kt += 32) {
    __syncthreads();
#pragma unroll
    for (int p = 0; p < 2; ++p) {
      const int i = tid + p * 256;
      const int row = i >> 2, q = i & 3;
      *(uint4*)&As[row * 40 + q * 8] = *(const uint4*)&U[(size_t)(r0 + row) * K3 + kt + q * 8];
    }
    *(uint4*)&Bs[a_row * 40 + a_q * 8] = *(const uint4*)&WcB[(size_t)(g0 + a_row) * K3 + kt + a_q * 8];
    __syncthreads();
    short8 af[4], bfr[2];
#pragma unroll
    for (int mf = 0; mf < 4; ++mf)
      af[mf] = *(const short8*)&As[(wm * 64 + mf * 16 + l15) * 40 + quad * 8];
#pragma unroll
    for (int nt = 0; nt < 2; ++nt)
      bfr[nt] = *(const short8*)&Bs[(wn * 32 + nt * 16 + l15) * 40 + quad * 8];
#pragma unroll
    for (int mf = 0; mf < 4; ++mf)
#pragma unroll
      for (int nt = 0; nt < 2; ++nt)
        acc[mf][nt] = __builtin_amdgcn_mfma_f32_16x16x32_bf16(af[mf], bfr[nt], acc[mf][nt], 0, 0, 0);
  }
#pragma unroll
  for (int nt = 0; nt < 2; ++nt) {
    const int col = g0 + wn * 32 + nt * 16 + l15;
    const float bias = bc[col];
#pragma unroll
    for (int mf = 0; mf < 4; ++mf)
#pragma unroll
      for (int i = 0; i < 4; ++i) {
        const int row = r0 + wm * 64 + mf * 16 + quad * 4 + i;
        gB[(size_t)row * H5 + col] = acc[mf][nt][i] + bias;
      }
  }
}

// ---------------- one LSTM timestep, MFMA version ----------------
__global__ __launch_bounds__(256)
void k_stepm(const float* __restrict__ Xf, const float* __restrict__ Xb,
             const unsigned short* __restrict__ WhfB, const unsigned short* __restrict__ WhbB,
             const float* __restrict__ bf, const float* __restrict__ bb,
             const int* __restrict__ len,
             unsigned short* __restrict__ hbB, float* __restrict__ cbuf,
             float* __restrict__ hs, float* __restrict__ cs, int t)
{
  const int dir = blockIdx.y;
  const int hjt = blockIdx.x;
  const int tid = threadIdx.x;
  const int wave = tid >> 6, lane = tid & 63;
  const int l15 = lane & 15, quad = lane >> 4;
  const unsigned short* Wh = dir ? WhbB : WhfB;
  const float* bias = dir ? bb : bf;
  const float* X = dir ? Xb : Xf;
  const int pp = t & 1;
  const unsigned short* hp = hbB + (size_t)(dir * 2 + pp) * 8192;
  unsigned short* hn = hbB + (size_t)(dir * 2 + (pp ^ 1)) * 8192;
  const float* cp = cbuf + (size_t)(dir * 2 + pp) * 8192;
  float* cn = cbuf + (size_t)(dir * 2 + (pp ^ 1)) * 8192;

  __shared__ float sg[4 * 16 * 17];
  floatx4 acc = (floatx4){0.f, 0.f, 0.f, 0.f};
  const int jg = wave * 512 + hjt * 16 + l15;
  for (int kt = 0; kt < 512; kt += 32) {
    const short8 a = *(const short8*)&hp[(size_t)l15 * 512 + kt + quad * 8];
    const short8 b = *(const short8*)&Wh[(size_t)jg * 512 + kt + quad * 8];
    acc = __builtin_amdgcn_mfma_f32_16x16x32_bf16(a, b, acc, 0, 0, 0);
  }
#pragma unroll
  for (int i = 0; i < 4; ++i)
    sg[wave * 272 + (quad * 4 + i) * 17 + l15] = acc[i];
  __syncthreads();
  const int b = tid >> 4, j = tid & 15;
  const int hj = hjt * 16 + j;
  const int Lb = len[b];
  int xidx = t;
  if (dir) xidx = (t < Lb) ? (Lb - 1 - t) : t;
  const float* xr = X + (size_t)(b * SL + xidx) * 2048;
  const float gi = sg[0 * 272 + b * 17 + j] + xr[hj] + bias[hj];
  const float gf = sg[1 * 272 + b * 17 + j] + xr[512 + hj] + bias[512 + hj];
  const float gg = sg[2 * 272 + b * 17 + j] + xr[1024 + hj] + bias[1024 + hj];
  const float go = sg[3 * 272 + b * 17 + j] + xr[1536 + hj] + bias[1536 + hj];
  const float cprev = cp[b * 512 + hj];
  const float cnew = sigf(gf) * cprev + sigf(gi) * tanhf(gg);
  const float hnew = sigf(go) * tanhf(cnew);
  cn[b * 512 + hj] = cnew;
  hn[b * 512 + hj] = f2bf(hnew);
  const int pos = dir ? xidx : t;
  const int col = dir ? (512 + hj) : hj;
  hs[(size_t)(b * SL + pos) * 1024 + col] = hnew;
  cs[(size_t)(b * SL + pos) * 1024 + col] = cnew;
}

// ---------------- precompute ALL segment argmax splits ----------------
// grid (16 sentences, 31 start positions), block 256. Same summation order as
// the old k_tree (per-32 partials, 8-group sum) -> bit-identical argmax.
__global__ __launch_bounds__(256)
void k_score(const float* __restrict__ E1, const float* __restrict__ Wr1,
             const float* __restrict__ Wr2, const int* __restrict__ len,
             int* __restrict__ ksplit)
{
  const int b = blockIdx.x;
  const int s = blockIdx.y;
  const int L = len[b];
  if (s + 2 > L) return;
  const int tid = threadIdx.x;
  __shared__ float e[32 * 257];
  __shared__ float w1p[256];
  __shared__ float w2s[256];
  __shared__ float red[32 * 8];
  __shared__ float sc[32];
  const int nrow = 32 - s;
  for (int i = tid; i < nrow * 256; i += 256) {
    const int rr = i >> 8, q = i & 255;
    e[rr * 257 + q] = E1[(size_t)(b * SL + s + rr) * 256 + q];
  }
  w1p[tid] = Wr1[tid * 513 + 512];
  w2s[tid] = Wr2[tid];
  __syncthreads();
  const int t_ = tid & 31, jg = tid >> 5;
  const int lmax = L - s;
  for (int l = 2; l <= lmax; ++l) {
    float part = 0.0f;
    if (t_ < l) {
      const float pos = 2.0f * (float)t_ / (float)l - 1.0f;
      const float* er = e + t_ * 257;
      for (int q = jg * 32; q < jg * 32 + 32; ++q) {
        const float v = er[q] + pos * w1p[q];
        part += fmaxf(v, 0.0f) * w2s[q];
      }
    }
    red[t_ * 8 + jg] = part;
    __syncthreads();
    if (jg == 0 && t_ < l) {
      float su = 0.0f;
      for (int q = 0; q < 8; ++q) su += red[t_ * 8 + q];
      sc[t_] = su;
    }
    __syncthreads();
    if (tid == 0) {
      int k = 0;
      float best = sc[0];
      for (int q = 1; q < l; ++q)
        if (sc[q] > best) { best = sc[q]; k = q; }
      ksplit[(b * 32 + s) * 33 + l] = k;
    }
    __syncthreads();
  }
}

// ---------------- DFS walk using precomputed splits ----------------
// grid 16 (one block per sentence), block 64; thread 0 walks from LDS table.
__global__ __launch_bounds__(64)
void k_walk(const int* __restrict__ ksplit, const int* __restrict__ len,
            int* __restrict__ meta)
{
  const int b = blockIdx.x;
  const int tid = threadIdx.x;
  __shared__ int ks[32 * 33];
  __shared__ int stk[96];
  for (int i = tid; i < 32 * 33; i += 64) ks[i] = ksplit[b * 1056 + i];
  __syncthreads();
  if (tid != 0) return;
  int* own = meta;
  int* lt = meta + 512;
  int* li = meta + 1024;
  int* rt = meta + 1536;
  int* ri = meta + 2048;
  int* dep = meta + 2560;
  int* nn = meta + 3072;
  int* dcnt = meta + 3088;
  int* lcnt = meta + 3120;
  int* dlist = meta + 3152;
  int* llist = meta + 19536;
  int sp = 0, nn_ = 1;
  stk[0] = 0; stk[1] = len[b]; stk[2] = 0;
  sp = 1;
  while (sp > 0) {
    sp--;
    const int s = stk[sp * 3], eN = stk[sp * 3 + 1], nid = stk[sp * 3 + 2];
    const int l = eN - s;
    const int k = ks[s * 33 + l];
    const int m = b * 32 + nid;
    own[m] = s + k;
    if (k == 0) { lt[m] = 0; li[m] = 0; }
    else if (k == 1) { lt[m] = 1; li[m] = s; }
    else {
      const int id = nn_++;
      lt[m] = 2; li[m] = id;
      stk[sp * 3] = s; stk[sp * 3 + 1] = s + k; stk[sp * 3 + 2] = id; sp++;
    }
    const int rl = l - k - 1;
    if (rl == 0) { rt[m] = 0; ri[m] = 0; }
    else if (rl == 1) { rt[m] = 1; ri[m] = s + k + 1; }
    else {
      const int id = nn_++;
      rt[m] = 2; ri[m] = id;
      stk[sp * 3] = s + k + 1; stk[sp * 3 + 1] = eN; stk[sp * 3 + 2] = id; sp++;
    }
  }
  nn[b] = nn_;
  for (int i = nn_ - 1; i >= 0; --i) {
    const int m = b * 32 + i;
    int d = 1;
    if (lt[m] == 2) d = max(d, dep[b * 32 + li[m]] + 1);
    if (rt[m] == 2) d = max(d, dep[b * 32 + ri[m]] + 1);
    dep[m] = d;
  }
  for (int i = 0; i < nn_; ++i) {
    const int m = b * 32 + i;
    const int r = dep[m];
    const int idx = atomicAdd(&dcnt[r], 1);
    dlist[r * 512 + idx] = m;
    if (lt[m] == 2 || rt[m] == 2) {
      const int lx = atomicAdd(&lcnt[r], 1);
      llist[r * 512 + lx] = m;
    }
  }
}

// ---------------- build U (bf16) = [hl_leaf|0 , hr_leaf|0 , hx] per node ----------------
__global__ __launch_bounds__(256)
void k_ubuild(const float* __restrict__ hs, const int* __restrict__ meta,
              unsigned short* __restrict__ U)
{
  const int id = blockIdx.x, b = blockIdx.y;
  const int tid = threadIdx.x;
  const int* own = meta;
  const int* lt = meta + 512;
  const int* li = meta + 1024;
  const int* rt = meta + 1536;
  const int* ri = meta + 2048;
  const int* nn = meta + 3072;
  const int m = b * 32 + id;
  unsigned short* u = U + (size_t)m * K3;
  if (id >= nn[b]) {
    for (int i = tid; i < K3; i += 256) u[i] = 0;
    return;
  }
  const float* hl = (lt[m] == 1) ? hs + (size_t)(b * 32 + li[m]) * 1024 : nullptr;
  const float* hr = (rt[m] == 1) ? hs + (size_t)(b * 32 + ri[m]) * 1024 : nullptr;
  const float* hx = hs + (size_t)(b * 32 + own[m]) * 1024;
  for (int i = tid; i < 1024; i += 256) {
    u[i] = hl ? f2bf(hl[i]) : 0;
    u[1024 + i] = hr ? f2bf(hr[i]) : 0;
    u[2048 + i] = f2bf(hx[i]);
  }
}

// ---------------- fused round r>=2: link MFMA (all 5 gates) + gating ----------------
// grid (16 j-tiles of 64, 4 m-chunk streams), block 256 (4 waves x 5 n-frags).
__global__ __launch_bounds__(256)
void k_round2(const unsigned short* __restrict__ WcB, const int* __restrict__ meta,
              const unsigned short* __restrict__ nodehbI, const float* __restrict__ gB,
              const float* __restrict__ cs, float* __restrict__ nodeh,
              float* __restrict__ nodec, unsigned short* __restrict__ nodehbO, int r)
{
  const int* lt = meta + 512;
  const int* li = meta + 1024;
  const int* rt = meta + 1536;
  const int* ri = meta + 2048;
  const int* lcnt = meta + 3120;
  const int* llist = meta + 19536;
  const int cnt = lcnt[r];
  if (cnt == 0) return;
  const int jt = blockIdx.x;
  const int j0 = jt * 64;
  __shared__ __align__(16) unsigned short As[16 * 40];
  __shared__ __align__(16) unsigned short Bs[320 * 40];
  __shared__ float sg[16 * 321];
  __shared__ int snode[16];
  __shared__ int sofs[2][16];
  const int tid = threadIdx.x;
  const int wave = tid >> 6, lane = tid & 63;
  const int l15 = lane & 15, quad = lane >> 4;
  const uint4 z4 = make_uint4(0, 0, 0, 0);

  for (int mc = blockIdx.y; mc * 16 < cnt; mc += gridDim.y) {
    const int m0 = mc * 16;
    __syncthreads();
    if (tid < 16) {
      int node = -1, ol = -1, orr = -1;
      if (m0 + tid < cnt) {
        node = llist[r * 512 + m0 + tid];
        const int base = node & ~31;
        if (lt[node] == 2) ol = (base + li[node]) * 1024;
        if (rt[node] == 2) orr = (base + ri[node]) * 1024;
      }
      snode[tid] = node;
      sofs[0][tid] = ol;
      sofs[1][tid] = orr;
    }
    __syncthreads();
    floatx4 acc[5];
#pragma unroll
    for (int f = 0; f < 5; ++f) acc[f] = (floatx4){0.f, 0.f, 0.f, 0.f};
    for (int kt = 0; kt < 2048; kt += 32) {
      __syncthreads();
      if (tid < 64) {
        const int row = tid >> 2, q = tid & 3;
        const int kk = kt + q * 8;
        const int side = kk >> 10, kl = kk & 1023;
        const int ofs = sofs[side][row];
        *(uint4*)&As[row * 40 + q * 8] =
            (ofs >= 0) ? *(const uint4*)&nodehbI[(size_t)ofs + kl] : z4;
      }
#pragma unroll
      for (int p = 0; p < 5; ++p) {
        const int i = tid + p * 256;
        const int row = i >> 2, q = i & 3;
        const int g = row >> 6, jr = row & 63;
        *(uint4*)&Bs[row * 40 + q * 8] =
            *(const uint4*)&WcB[(size_t)(g * 1024 + j0 + jr) * K3 + kt + q * 8];
      }
      __syncthreads();
      const short8 a = *(const short8*)&As[l15 * 40 + quad * 8];
#pragma unroll
      for (int f = 0; f < 5; ++f) {
        const int nf = wave * 5 + f;
        const short8 bb = *(const short8*)&Bs[(nf * 16 + l15) * 40 + quad * 8];
        acc[f] = __builtin_amdgcn_mfma_f32_16x16x32_bf16(a, bb, acc[f], 0, 0, 0);
      }
    }
    __syncthreads();
#pragma unroll
    for (int f = 0; f < 5; ++f) {
      const int ncol = (wave * 5 + f) * 16 + l15;
#pragma unroll
      for (int i = 0; i < 4; ++i)
        sg[(quad * 4 + i) * 321 + ncol] = acc[f][i];
    }
    __syncthreads();
    const int m = tid >> 4;
    if (m0 + m < cnt) {
      const int node = snode[m];
      const int base = node & ~31;
      const int ltv = lt[node], rtv = rt[node];
      const float* clp = (ltv == 2) ? &nodec[(size_t)(base + li[node]) * 1024]
                       : (ltv == 1) ? &cs[(size_t)(base + li[node]) * 1024] : nullptr;
      const float* crp = (rtv == 2) ? &nodec[(size_t)(base + ri[node]) * 1024]
                       : (rtv == 1) ? &cs[(size_t)(base + ri[node]) * 1024] : nullptr;
      const float* gb = &gB[(size_t)node * H5];
#pragma unroll
      for (int q = 0; q < 4; ++q) {
        const int j = (tid & 15) * 4 + q;
        const int hj = j0 + j;
        const float gi = sg[m * 321 + 0 * 64 + j] + gb[0 * 1024 + hj];
        const float gfl = sg[m * 321 + 1 * 64 + j] + gb[1 * 1024 + hj];
        const float gfr = sg[m * 321 + 2 * 64 + j] + gb[2 * 1024 + hj];
        const float gu = sg[m * 321 + 3 * 64 + j] + gb[3 * 1024 + hj];
        const float go = sg[m * 321 + 4 * 64 + j] + gb[4 * 1024 + hj];
        const float cl = clp ? clp[hj] : 0.0f;
        const float cr = crp ? crp[hj] : 0.0f;
        const float c = sigf(gfl) * cl + sigf(gfr) * cr + sigf(gi) * tanhf(gu);
        const float h = sigf(go) * tanhf(c);
        nodeh[(size_t)node * 1024 + hj] = h;
        nodec[(size_t)node * 1024 + hj] = c;
        nodehbO[(size_t)node * 1024 + hj] = f2bf(h);
      }
    }
  }
}

// ---------------- gate-only (round 1: all children are leaves) ----------------
__global__ void k_gate(const float* __restrict__ gB, const float* __restrict__ cs,
                       const int* __restrict__ meta, float* __restrict__ nodeh,
                       float* __restrict__ nodec, unsigned short* __restrict__ nodehb, int r)
{
  const int* lt = meta + 512;
  const int* li = meta + 1024;
  const int* rt = meta + 1536;
  const int* ri = meta + 2048;
  const int* dcnt = meta + 3088;
  const int* dlist = meta + 3152;
  const int cnt = dcnt[r];
  const int m = blockIdx.x;
  if (m >= cnt) return;
  const int node = dlist[r * 512 + m];
  const int base = node & ~31;
  const int ltv = lt[node], rtv = rt[node];
  const float* clp = (ltv == 2) ? &nodec[(size_t)(base + li[node]) * 1024]
                   : (ltv == 1) ? &cs[(size_t)(base + li[node]) * 1024] : nullptr;
  const float* crp = (rtv == 2) ? &nodec[(size_t)(base + ri[node]) * 1024]
                   : (rtv == 1) ? &cs[(size_t)(base + ri[node]) * 1024] : nullptr;
  const float* g = &gB[(size_t)node * H5];
  for (int j = threadIdx.x; j < 1024; j += 256) {
    const float gi = g[j];
    const float gfl = g[1024 + j];
    const float gfr = g[2048 + j];
    const float gu = g[3072 + j];
    const float go = g[4096 + j];
    const float cl = clp ? clp[j] : 0.0f;
    const float cr = crp ? crp[j] : 0.0f;
    const float c = sigf(gfl) * cl + sigf(gfr) * cr + sigf(gi) * tanhf(gu);
    const float h = sigf(go) * tanhf(c);
    nodeh[(size_t)node * 1024 + j] = h;
    nodec[(size_t)node * 1024 + j] = c;
    nodehb[(size_t)node * 1024 + j] = f2bf(h);
  }
}

// ---------------- gather roots ----------------
__global__ void k_out(const float* __restrict__ nodeh, const float* __restrict__ nodec,
                      float* __restrict__ out)
{
  const int b = blockIdx.x;
  const int tid = threadIdx.x;
  for (int i = tid; i < 1024; i += 256) {
    out[b * 1024 + i] = nodeh[(size_t)(b * 32) * 1024 + i];
    out[16384 + b * 1024 + i] = nodec[(size_t)(b * 32) * 1024 + i];
  }
}

extern "C" void kernel_launch(void* const* d_in, const int* in_sizes, int n_in,
                              void* d_out, int out_size, void* d_ws, size_t ws_size,
                              hipStream_t stream) {
  const float* emb = (const float*)d_in[0];
  const int* len = (const int*)d_in[1];
  const float* Wihf = (const float*)d_in[2];
  const float* Whhf = (const float*)d_in[3];
  const float* bf = (const float*)d_in[4];
  const float* Wihb = (const float*)d_in[5];
  const float* Whhb = (const float*)d_in[6];
  const float* bb = (const float*)d_in[7];
  const float* Wr1 = (const float*)d_in[8];
  const float* Wr2 = (const float*)d_in[9];
  const float* Wc = (const float*)d_in[10];
  const float* bc = (const float*)d_in[11];
  float* out = (float*)d_out;

  float* ws = (float*)d_ws;
  float* Xf = ws;                                         // 1048576 f
  float* Xb = Xf + 1048576;                               // 1048576 f
  float* hs = Xb + 1048576;                               // 524288 f
  float* cs = hs + 524288;                                // 524288 f
  float* E1 = cs + 524288;                                // 131072 f
  unsigned short* U = (unsigned short*)(E1 + 131072);     // 786432 f
  float* gB = (float*)U + 786432;                         // 2621440 f
  float* nodeh = gB + 2621440;                            // 524288 f
  float* nodec = nodeh + 524288;                          // 524288 f
  unsigned short* nodehb = (unsigned short*)(nodec + 524288);     // 262144 f
  float* cbuf = (float*)nodehb + 262144;                  // 32768 f
  unsigned short* hbB = (unsigned short*)(cbuf + 32768);  // 16384 f
  unsigned short* WcB = (unsigned short*)((float*)hbB + 16384);   // 7864320 f
  unsigned short* WihfB = WcB + 15728640;                 // 1048576 sh
  unsigned short* WihbB = WihfB + 1048576;
  unsigned short* WhhfB = WihbB + 1048576;
  unsigned short* WhhbB = WhhfB + 1048576;
  unsigned short* embB = WhhbB + 1048576;                 // 262144 sh
  int* meta = (int*)(embB + 262144);                      // ~36K ints
  int* ksplit = meta + 36096;                             // 16*1056 ints

  // zero c/h ping-pong state and per-depth counters
  k_zero<<<192, 256, 0, stream>>>(cbuf, 49152);
  k_zero<<<1, 64, 0, stream>>>((float*)(meta + 3088), 64);
  // bf16 conversions
  k_conv6<<<dim3(1920, 6), 256, 0, stream>>>(
      Wc, WcB, 15728640, Wihf, WihfB, 1048576, Wihb, WihbB, 1048576,
      Whhf, WhhfB, 1048576, Whhb, WhhbB, 1048576, emb, embB, 262144);
  // rank projection (f32)
  k_gemm<<<dim3(4, 8), 256, 0, stream>>>(emb, 512, Wr1, 513, E1, 256, 512);
  // input projections
  k_xproj<<<dim3(16, 4, 2), 256, 0, stream>>>(embB, WihfB, WihbB, Xf, Xb);
  // recurrent scan
  for (int t = 0; t < SL; ++t)
    k_stepm<<<dim3(32, 2), 256, 0, stream>>>(Xf, Xb, WhhfB, WhhbB, bf, bb, len,
                                             hbB, cbuf, hs, cs, t);
  // split table (parallel) + DFS walk (cheap)
  k_score<<<dim3(16, 31), 256, 0, stream>>>(E1, Wr1, Wr2, len, ksplit);
  k_walk<<<16, 64, 0, stream>>>(ksplit, len, meta);
  // precomputable part of every compose
  k_ubuild<<<dim3(32, 16), 256, 0, stream>>>(hs, meta, U);
  k_mfma_gemm<<<320, 256, 0, stream>>>(U, WcB, bc, gB);
  // round 1: gate-only (all children are leaves)
  k_gate<<<512, 256, 0, stream>>>(gB, cs, meta, nodeh, nodec, nodehb, 1);
  // rounds >=2: fused link-GEMM + gating
  for (int r = 2; r <= 31; ++r)
    k_round2<<<dim3(16, 4), 256, 0, stream>>>(WcB, meta, nodehb, gB, cs,
                                              nodeh, nodec, nodehb, r);
  k_out<<<16, 256, 0, stream>>>(nodeh, nodec, out);
}